// Round 1
// baseline (1396.760 us; speedup 1.0000x reference)
//
#include <hip/hip_runtime.h>
#include <hip/hip_fp16.h>

// LSTMPredictor: B=1024, T=512, IN=19, H=128, OUT=7 (fp32 in/out)
// Two sequential persistent kernels: layer1 -> h1 (fp16, 134MB ws) -> layer2+linear.
// 256 blocks x 512 threads; 4 batch rows/block; weights live in registers as
// fp16 MFMA B-fragments; h state in LDS double buffer (XOR-swizzled), c in regs.

typedef _Float16 half8 __attribute__((ext_vector_type(8)));
typedef float f32x4 __attribute__((ext_vector_type(4)));

#define MFMA16(a, b, c) __builtin_amdgcn_mfma_f32_16x16x32_f16((a), (b), (c), 0, 0, 0)

__device__ __forceinline__ float fast_sig(float x) {
  x = fminf(fmaxf(x, -30.f), 30.f);
  return __builtin_amdgcn_rcpf(1.f + __expf(-x));
}
__device__ __forceinline__ float fast_tanh(float x) {
  x = fminf(fmaxf(x, -15.f), 15.f);
  const float e = __expf(-2.f * x);
  return (1.f - e) * __builtin_amdgcn_rcpf(1.f + e);
}

__device__ __forceinline__ half8 zero_h8() {
  half8 f;
#pragma unroll
  for (int j = 0; j < 8; ++j) f[j] = (_Float16)0.f;
  return f;
}

// ---------------- Layer 1 ----------------
__global__ __launch_bounds__(512, 2) void lstm_layer1_kernel(
    const float* __restrict__ x,        // [1024,512,19]
    const float* __restrict__ Wih,      // [512,19]
    const float* __restrict__ Whh,      // [512,128]
    const float* __restrict__ bih, const float* __restrict__ bhh,
    _Float16* __restrict__ h1g)         // [256][512][4][128] fp16
{
  __shared__ _Float16 hbuf[2][2048];    // [buf][row*128 + swizzled col]
  const int tid = threadIdx.x, bid = blockIdx.x;
  const int wave = tid >> 6, lane = tid & 63;
  const int lg = lane >> 4, lc = lane & 15;

  // Weight fragments (B operand): col = tile*16+lc, k = lg*8+j (contiguous k)
  half8 wih_f[4];
  half8 whh_f[4][4];
  float bias[4];
#pragma unroll
  for (int g = 0; g < 4; ++g) {
    const int n = (wave + 8 * g) * 16 + lc;   // gate column 0..511 (i,f,g,o strided)
    bias[g] = bih[n] + bhh[n];
    half8 f = zero_h8();
#pragma unroll
    for (int j = 0; j < 8; ++j) {
      const int k = lg * 8 + j;
      if (k < 19) f[j] = (_Float16)Wih[n * 19 + k];
    }
    wih_f[g] = f;
#pragma unroll
    for (int kk = 0; kk < 4; ++kk) {
      const float* p = Whh + n * 128 + kk * 32 + lg * 8;
      half8 f2;
#pragma unroll
      for (int j = 0; j < 8; ++j) f2[j] = (_Float16)p[j];
      whh_f[g][kk] = f2;
    }
  }

  for (int i = tid; i < 2 * 2048; i += 512) ((_Float16*)hbuf)[i] = (_Float16)0.f;

  float c = 0.f;
  const int jh = wave * 16 + lc;   // hidden unit owned by this lane
  const int row = lg;              // batch row owned (0..3)

  const bool xvalid = (lc < 4);
  const int arow = xvalid ? lc : 3;
  const float* xrow = x + (size_t)(bid * 4 + arow) * 512 * 19;

  // preload x frag for t=0 (A operand: row=lc, k=lg*8+j, pad k>=19 with 0)
  half8 ax = zero_h8();
  if (xvalid) {
#pragma unroll
    for (int j = 0; j < 8; ++j) {
      const int k = lg * 8 + j;
      if (k < 19) ax[j] = (_Float16)xrow[k];
    }
  }
  __syncthreads();

  const int sw = (lc & 7) << 3;
  for (int t = 0; t < 512; ++t) {
    const _Float16* rd = hbuf[(t & 1) ^ 1];
    const int rb = lc * 128;
    const half8 ah0 = *(const half8*)(rd + rb + ((0  + lg * 8) ^ sw));
    const half8 ah1 = *(const half8*)(rd + rb + ((32 + lg * 8) ^ sw));
    const half8 ah2 = *(const half8*)(rd + rb + ((64 + lg * 8) ^ sw));
    const half8 ah3 = *(const half8*)(rd + rb + ((96 + lg * 8) ^ sw));

    // prefetch next step's x fragment (hides HBM latency under MFMA)
    half8 axn = zero_h8();
    if (xvalid && t + 1 < 512) {
      const float* px = xrow + (size_t)(t + 1) * 19;
#pragma unroll
      for (int j = 0; j < 8; ++j) {
        const int k = lg * 8 + j;
        if (k < 19) axn[j] = (_Float16)px[k];
      }
    }

    f32x4 acc[4];
#pragma unroll
    for (int g = 0; g < 4; ++g) {
      f32x4 a = {bias[g], bias[g], bias[g], bias[g]};
      a = MFMA16(ax,  wih_f[g],    a);
      a = MFMA16(ah0, whh_f[g][0], a);
      a = MFMA16(ah1, whh_f[g][1], a);
      a = MFMA16(ah2, whh_f[g][2], a);
      a = MFMA16(ah3, whh_f[g][3], a);
      acc[g] = a;
    }

    // repack: lane <- gate values for (row=lg, col=lc of this wave's slice).
    // Source: D layout col=lane&15,row=(lane>>4)*4+reg -> src lane = lc, reg = lg.
    float gv[4];
#pragma unroll
    for (int g = 0; g < 4; ++g) {
      const float v0 = __shfl(acc[g][0], lc, 64);
      const float v1 = __shfl(acc[g][1], lc, 64);
      const float v2 = __shfl(acc[g][2], lc, 64);
      const float v3 = __shfl(acc[g][3], lc, 64);
      gv[g] = (lg == 0) ? v0 : (lg == 1) ? v1 : (lg == 2) ? v2 : v3;
    }
    const float ig = fast_sig(gv[0]);
    const float fg = fast_sig(gv[1]);
    const float gg = fast_tanh(gv[2]);
    const float og = fast_sig(gv[3]);
    c = fg * c + ig * gg;
    const float h = og * fast_tanh(c);
    const _Float16 h16 = (_Float16)h;

    _Float16* wr = hbuf[t & 1];
    wr[row * 128 + (jh ^ (row << 3))] = h16;
    h1g[(((size_t)bid * 512 + t) * 4 + row) * 128 + jh] = h16;

    ax = axn;
    __syncthreads();
  }
}

// ---------------- Layer 2 + Linear ----------------
__global__ __launch_bounds__(512, 2) void lstm_layer2_kernel(
    const _Float16* __restrict__ h1g,   // [256][512][4][128] fp16
    const float* __restrict__ Wih,      // [512,128] (input = h1)
    const float* __restrict__ Whh,      // [512,128]
    const float* __restrict__ bih, const float* __restrict__ bhh,
    const float* __restrict__ Wlin,     // [7,128]
    const float* __restrict__ blin,     // [7]
    float* __restrict__ out)            // [1024, 3584]
{
  __shared__ _Float16 hbuf[2][2048];
  const int tid = threadIdx.x, bid = blockIdx.x;
  const int wave = tid >> 6, lane = tid & 63;
  const int lg = lane >> 4, lc = lane & 15;

  half8 wi_f[4][4], wh_f[4][4];
  float bias[4];
#pragma unroll
  for (int g = 0; g < 4; ++g) {
    const int n = (wave + 8 * g) * 16 + lc;
    bias[g] = bih[n] + bhh[n];
#pragma unroll
    for (int kk = 0; kk < 4; ++kk) {
      const float* pi = Wih + n * 128 + kk * 32 + lg * 8;
      const float* ph = Whh + n * 128 + kk * 32 + lg * 8;
      half8 fi, fh;
#pragma unroll
      for (int j = 0; j < 8; ++j) { fi[j] = (_Float16)pi[j]; fh[j] = (_Float16)ph[j]; }
      wi_f[g][kk] = fi;
      wh_f[g][kk] = fh;
    }
  }
  // W_lin fragments (col = lc, valid lc<7)
  half8 wl_f[4];
  float ybias = 0.f;
  {
    const bool v = (lc < 7);
    if (v) ybias = blin[lc];
#pragma unroll
    for (int kk = 0; kk < 4; ++kk) {
      half8 f = zero_h8();
      if (v) {
#pragma unroll
        for (int j = 0; j < 8; ++j) f[j] = (_Float16)Wlin[lc * 128 + kk * 32 + lg * 8 + j];
      }
      wl_f[kk] = f;
    }
  }

  for (int i = tid; i < 2 * 2048; i += 512) ((_Float16*)hbuf)[i] = (_Float16)0.f;

  float c = 0.f;
  const int jh = wave * 16 + lc;
  const int row = lg;
  const bool h1valid = (lc < 4);
  const int arow = h1valid ? lc : 3;
  // per-t stride = 4*128 = 512 halfs
  const _Float16* h1p = h1g + (size_t)bid * 262144 + (size_t)arow * 128 + lg * 8;

  half8 a1c0 = zero_h8(), a1c1 = zero_h8(), a1c2 = zero_h8(), a1c3 = zero_h8();
  if (h1valid) {
    a1c0 = *(const half8*)(h1p + 0);
    a1c1 = *(const half8*)(h1p + 32);
    a1c2 = *(const half8*)(h1p + 64);
    a1c3 = *(const half8*)(h1p + 96);
  }
  __syncthreads();

  const int sw = (lc & 7) << 3;
  for (int t = 0; t < 512; ++t) {
    const _Float16* rd = hbuf[(t & 1) ^ 1];
    const int rb = lc * 128;
    const half8 b0 = *(const half8*)(rd + rb + ((0  + lg * 8) ^ sw));
    const half8 b1 = *(const half8*)(rd + rb + ((32 + lg * 8) ^ sw));
    const half8 b2 = *(const half8*)(rd + rb + ((64 + lg * 8) ^ sw));
    const half8 b3 = *(const half8*)(rd + rb + ((96 + lg * 8) ^ sw));

    half8 a1n0 = zero_h8(), a1n1 = zero_h8(), a1n2 = zero_h8(), a1n3 = zero_h8();
    if (h1valid && t + 1 < 512) {
      const _Float16* p = h1p + (size_t)(t + 1) * 512;
      a1n0 = *(const half8*)(p + 0);
      a1n1 = *(const half8*)(p + 32);
      a1n2 = *(const half8*)(p + 64);
      a1n3 = *(const half8*)(p + 96);
    }

    f32x4 acc[4];
#pragma unroll
    for (int g = 0; g < 4; ++g) {
      f32x4 a = {bias[g], bias[g], bias[g], bias[g]};
      a = MFMA16(a1c0, wi_f[g][0], a);
      a = MFMA16(a1c1, wi_f[g][1], a);
      a = MFMA16(a1c2, wi_f[g][2], a);
      a = MFMA16(a1c3, wi_f[g][3], a);
      a = MFMA16(b0, wh_f[g][0], a);
      a = MFMA16(b1, wh_f[g][1], a);
      a = MFMA16(b2, wh_f[g][2], a);
      a = MFMA16(b3, wh_f[g][3], a);
      acc[g] = a;
    }

    // y(t-1) = h2(t-1) @ Wlin^T + b  (b-frags hold h2(t-1)); wave 0 only
    if (wave == 0 && t > 0) {
      f32x4 ya = {ybias, ybias, ybias, ybias};
      ya = MFMA16(b0, wl_f[0], ya);
      ya = MFMA16(b1, wl_f[1], ya);
      ya = MFMA16(b2, wl_f[2], ya);
      ya = MFMA16(b3, wl_f[3], ya);
      if (lg == 0 && lc < 7) {
#pragma unroll
        for (int j = 0; j < 4; ++j)
          out[(size_t)(bid * 4 + j) * 3584 + (size_t)(t - 1) * 7 + lc] = ya[j];
      }
    }

    float gv[4];
#pragma unroll
    for (int g = 0; g < 4; ++g) {
      const float v0 = __shfl(acc[g][0], lc, 64);
      const float v1 = __shfl(acc[g][1], lc, 64);
      const float v2 = __shfl(acc[g][2], lc, 64);
      const float v3 = __shfl(acc[g][3], lc, 64);
      gv[g] = (lg == 0) ? v0 : (lg == 1) ? v1 : (lg == 2) ? v2 : v3;
    }
    const float ig = fast_sig(gv[0]);
    const float fg = fast_sig(gv[1]);
    const float gg = fast_tanh(gv[2]);
    const float og = fast_sig(gv[3]);
    c = fg * c + ig * gg;
    const float h = og * fast_tanh(c);

    _Float16* wr = hbuf[t & 1];
    wr[row * 128 + (jh ^ (row << 3))] = (_Float16)h;

    a1c0 = a1n0; a1c1 = a1n1; a1c2 = a1n2; a1c3 = a1n3;
    __syncthreads();
  }

  // final output y(511) from h2(511) (sits in hbuf[1]; last barrier already done)
  {
    const _Float16* rd = hbuf[1];
    const int rb = lc * 128;
    const half8 b0 = *(const half8*)(rd + rb + ((0  + lg * 8) ^ sw));
    const half8 b1 = *(const half8*)(rd + rb + ((32 + lg * 8) ^ sw));
    const half8 b2 = *(const half8*)(rd + rb + ((64 + lg * 8) ^ sw));
    const half8 b3 = *(const half8*)(rd + rb + ((96 + lg * 8) ^ sw));
    if (wave == 0) {
      f32x4 ya = {ybias, ybias, ybias, ybias};
      ya = MFMA16(b0, wl_f[0], ya);
      ya = MFMA16(b1, wl_f[1], ya);
      ya = MFMA16(b2, wl_f[2], ya);
      ya = MFMA16(b3, wl_f[3], ya);
      if (lg == 0 && lc < 7) {
#pragma unroll
        for (int j = 0; j < 4; ++j)
          out[(size_t)(bid * 4 + j) * 3584 + (size_t)511 * 7 + lc] = ya[j];
      }
    }
  }
}

extern "C" void kernel_launch(void* const* d_in, const int* in_sizes, int n_in,
                              void* d_out, int out_size, void* d_ws, size_t ws_size,
                              hipStream_t stream) {
  (void)in_sizes; (void)n_in; (void)out_size; (void)ws_size;
  const float* x     = (const float*)d_in[0];
  const float* W_ih1 = (const float*)d_in[1];
  const float* W_hh1 = (const float*)d_in[2];
  const float* b_ih1 = (const float*)d_in[3];
  const float* b_hh1 = (const float*)d_in[4];
  const float* W_ih2 = (const float*)d_in[5];
  const float* W_hh2 = (const float*)d_in[6];
  const float* b_ih2 = (const float*)d_in[7];
  const float* b_hh2 = (const float*)d_in[8];
  const float* W_lin = (const float*)d_in[9];
  const float* b_lin = (const float*)d_in[10];
  float* out = (float*)d_out;
  _Float16* h1g = (_Float16*)d_ws;   // needs 1024*512*128*2 = 134,217,728 bytes

  lstm_layer1_kernel<<<256, 512, 0, stream>>>(x, W_ih1, W_hh1, b_ih1, b_hh1, h1g);
  lstm_layer2_kernel<<<256, 512, 0, stream>>>(h1g, W_ih2, W_hh2, b_ih2, b_hh2,
                                              W_lin, b_lin, out);
}

// Round 2
// 1105.404 us; speedup vs baseline: 1.2636x; 1.2636x over previous
//
#include <hip/hip_runtime.h>

// LSTMPredictor: B=1024, T=512, IN=19, H=128, OUT=7 (fp32 in/out)
// L1: R=2 rows/block, 512 blocks, 2 blocks/CU resident (cross-block latency hiding).
// L2: R=4 rows/block, 256 blocks (weights need ~220 VGPR -> 2 waves/SIMD).
// No cross-lane repack: activations computed in MFMA D-layout on all lanes.
// Raw barrier (lgkmcnt only) so global stores/loads stay in flight across steps.

typedef _Float16 half8 __attribute__((ext_vector_type(8)));
typedef float f32x4 __attribute__((ext_vector_type(4)));

#define MFMA16(a, b, c) __builtin_amdgcn_mfma_f32_16x16x32_f16((a), (b), (c), 0, 0, 0)
#define BARRIER() asm volatile("s_waitcnt lgkmcnt(0)\ns_barrier" ::: "memory")

__device__ __forceinline__ float sigf(float x) {
  return __builtin_amdgcn_rcpf(1.f + __expf(-x));   // NaN-free at +/-inf
}
__device__ __forceinline__ float tanhf_(float x) {
  return 1.f - 2.f * __builtin_amdgcn_rcpf(1.f + __expf(2.f * x));  // NaN-free
}

// ---------------- Layer 1: R=2, 512 blocks ----------------
__global__ __launch_bounds__(512, 4) void lstm_layer1_kernel(
    const float* __restrict__ x,        // [1024,512,19]
    const float* __restrict__ Wih,      // [512,19]
    const float* __restrict__ Whh,      // [512,128]
    const float* __restrict__ bih, const float* __restrict__ bhh,
    _Float16* __restrict__ h1g)         // [512][1024][128]  (T-major)
{
  __shared__ _Float16 xs[512][2][32];   // 64KB: fp16 x-frags, k=19 slot = 1.0 (bias)
  __shared__ _Float16 hbuf[2][2][160];  // padded stride: rows land on disjoint banks
  const int tid = threadIdx.x, bid = blockIdx.x;
  const int wave = tid >> 6, lane = tid & 63;
  const int lg = lane >> 4, lc = lane & 15;

  // Weight B-frags: col n=(wave+8g)*16+lc, k=lg*8+j. Bias folded at k==19.
  half8 wih_f[4], whh_f[4][4];
#pragma unroll
  for (int g = 0; g < 4; ++g) {
    const int n = (wave + 8 * g) * 16 + lc;
    half8 f;
#pragma unroll
    for (int j = 0; j < 8; ++j) {
      const int k = lg * 8 + j;
      float v = 0.f;
      if (k < 19) v = Wih[n * 19 + k];
      else if (k == 19) v = bih[n] + bhh[n];
      f[j] = (_Float16)v;
    }
    wih_f[g] = f;
#pragma unroll
    for (int kk = 0; kk < 4; ++kk) {
      const float* p = Whh + n * 128 + kk * 32 + lg * 8;
      half8 f2;
#pragma unroll
      for (int j = 0; j < 8; ++j) f2[j] = (_Float16)p[j];
      whh_f[g][kk] = f2;
    }
  }

  // Stage x for rows {2bid, 2bid+1} into LDS as fp16 A-frag layout.
  {
    const float* xb = x + (size_t)bid * 2 * 512 * 19;
    for (int idx = tid; idx < 512 * 2 * 32; idx += 512) {
      const int t = idx >> 6, row = (idx >> 5) & 1, k = idx & 31;
      float v = 0.f;
      if (k < 19) v = xb[(size_t)row * (512 * 19) + t * 19 + k];
      else if (k == 19) v = 1.f;
      xs[t][row][k] = (_Float16)v;
    }
  }
  for (int i = tid; i < 2 * 2 * 160; i += 512) ((_Float16*)hbuf)[i] = (_Float16)0.f;
  __syncthreads();

  float c0 = 0.f, c1 = 0.f;
  const int hr = lc & 1;                 // A-frag row (lanes lc>=2 duplicate row)
  const int col = wave * 16 + lc;        // hidden unit owned at lg==0
  _Float16* h1p = h1g + (size_t)(2 * bid) * 128 + col;  // [t][row][col] stride t: 131072

  for (int t = 0; t < 512; ++t) {
    const _Float16* rd = &hbuf[(t & 1) ^ 1][hr][lg * 8];
    const half8 ax  = *(const half8*)&xs[t][hr][lg * 8];
    const half8 ah0 = *(const half8*)(rd + 0);
    const half8 ah1 = *(const half8*)(rd + 32);
    const half8 ah2 = *(const half8*)(rd + 64);
    const half8 ah3 = *(const half8*)(rd + 96);

    f32x4 acc[4];
#pragma unroll
    for (int g = 0; g < 4; ++g) {
      f32x4 a = {0.f, 0.f, 0.f, 0.f};
      a = MFMA16(ax,  wih_f[g],    a);
      a = MFMA16(ah0, whh_f[g][0], a);
      a = MFMA16(ah1, whh_f[g][1], a);
      a = MFMA16(ah2, whh_f[g][2], a);
      a = MFMA16(ah3, whh_f[g][3], a);
      acc[g] = a;
    }

    // D layout: row = lg*4 + reg, col = lc. Valid rows 0,1 live at lg==0, reg 0,1.
    // All lanes compute (garbage lanes harmless & finite); only lg==0 writes.
    const float i0 = sigf(acc[0][0]), f0 = sigf(acc[1][0]);
    const float g0 = tanhf_(acc[2][0]), o0 = sigf(acc[3][0]);
    c0 = f0 * c0 + i0 * g0;
    const float h0 = o0 * tanhf_(c0);
    const float i1 = sigf(acc[0][1]), f1 = sigf(acc[1][1]);
    const float g1 = tanhf_(acc[2][1]), o1 = sigf(acc[3][1]);
    c1 = f1 * c1 + i1 * g1;
    const float h1 = o1 * tanhf_(c1);

    if (lg == 0) {
      const _Float16 h0h = (_Float16)h0, h1h = (_Float16)h1;
      _Float16* wr = &hbuf[t & 1][0][0];
      wr[col] = h0h;
      wr[160 + col] = h1h;
      h1p[(size_t)t * 131072] = h0h;
      h1p[(size_t)t * 131072 + 128] = h1h;
    }
    BARRIER();
  }
}

// ---------------- Layer 2 + Linear: R=4, 256 blocks ----------------
__global__ __launch_bounds__(512, 2) void lstm_layer2_kernel(
    const _Float16* __restrict__ h1g,   // [512][1024][128]
    const float* __restrict__ Wih,      // [512,128]
    const float* __restrict__ Whh,      // [512,128]
    const float* __restrict__ bih, const float* __restrict__ bhh,
    const float* __restrict__ Wlin,     // [7,128]
    const float* __restrict__ blin,     // [7]
    float* __restrict__ out)            // [1024, 3584]
{
  __shared__ _Float16 hbuf[2][4][144];  // stride 144: 2-way max (free)
  const int tid = threadIdx.x, bid = blockIdx.x;
  const int wave = tid >> 6, lane = tid & 63;
  const int lg = lane >> 4, lc = lane & 15;

  half8 wi_f[4][4], wh_f[4][4];
  float bias[4];
#pragma unroll
  for (int g = 0; g < 4; ++g) {
    const int n = (wave + 8 * g) * 16 + lc;
    bias[g] = bih[n] + bhh[n];
#pragma unroll
    for (int kk = 0; kk < 4; ++kk) {
      const float* pi = Wih + n * 128 + kk * 32 + lg * 8;
      const float* ph = Whh + n * 128 + kk * 32 + lg * 8;
      half8 fi, fh;
#pragma unroll
      for (int j = 0; j < 8; ++j) { fi[j] = (_Float16)pi[j]; fh[j] = (_Float16)ph[j]; }
      wi_f[g][kk] = fi;
      wh_f[g][kk] = fh;
    }
  }
  half8 wl_f[4];
  float ybias = 0.f;
  {
    const bool v = (lc < 7);
    if (v) ybias = blin[lc];
#pragma unroll
    for (int kk = 0; kk < 4; ++kk) {
      half8 f;
#pragma unroll
      for (int j = 0; j < 8; ++j)
        f[j] = v ? (_Float16)Wlin[lc * 128 + kk * 32 + lg * 8 + j] : (_Float16)0.f;
      wl_f[kk] = f;
    }
  }

  for (int i = tid; i < 2 * 4 * 144; i += 512) ((_Float16*)hbuf)[i] = (_Float16)0.f;

  float c[4] = {0.f, 0.f, 0.f, 0.f};
  const int col = wave * 16 + lc;
  const int ar = lc & 3;                // h1 A-frag row
  const _Float16* h1p = h1g + (size_t)(4 * bid + ar) * 128 + lg * 8;

  half8 a1c0 = *(const half8*)(h1p + 0);
  half8 a1c1 = *(const half8*)(h1p + 32);
  half8 a1c2 = *(const half8*)(h1p + 64);
  half8 a1c3 = *(const half8*)(h1p + 96);
  __syncthreads();

  for (int t = 0; t < 512; ++t) {
    const _Float16* rd = &hbuf[(t & 1) ^ 1][ar][lg * 8];
    const half8 b0 = *(const half8*)(rd + 0);
    const half8 b1 = *(const half8*)(rd + 32);
    const half8 b2 = *(const half8*)(rd + 64);
    const half8 b3 = *(const half8*)(rd + 96);

    // prefetch next step's h1 frags (T-major: step stride 1024*128)
    const size_t toff = (size_t)((t < 511) ? t + 1 : t) * 131072;
    const half8 a1n0 = *(const half8*)(h1p + toff + 0);
    const half8 a1n1 = *(const half8*)(h1p + toff + 32);
    const half8 a1n2 = *(const half8*)(h1p + toff + 64);
    const half8 a1n3 = *(const half8*)(h1p + toff + 96);

    f32x4 acc[4];
#pragma unroll
    for (int g = 0; g < 4; ++g) {
      f32x4 a = {bias[g], bias[g], bias[g], bias[g]};
      a = MFMA16(a1c0, wi_f[g][0], a);
      a = MFMA16(a1c1, wi_f[g][1], a);
      a = MFMA16(a1c2, wi_f[g][2], a);
      a = MFMA16(a1c3, wi_f[g][3], a);
      a = MFMA16(b0, wh_f[g][0], a);
      a = MFMA16(b1, wh_f[g][1], a);
      a = MFMA16(b2, wh_f[g][2], a);
      a = MFMA16(b3, wh_f[g][3], a);
      acc[g] = a;
    }

    // y(t-1) from h2(t-1) (b-frags), wave 0 only
    if (wave == 0 && t > 0) {
      f32x4 ya = {ybias, ybias, ybias, ybias};
      ya = MFMA16(b0, wl_f[0], ya);
      ya = MFMA16(b1, wl_f[1], ya);
      ya = MFMA16(b2, wl_f[2], ya);
      ya = MFMA16(b3, wl_f[3], ya);
      if (lg == 0 && lc < 7) {
#pragma unroll
        for (int j = 0; j < 4; ++j)
          out[(size_t)(bid * 4 + j) * 3584 + (size_t)(t - 1) * 7 + lc] = ya[j];
      }
    }

    // activations in D-layout: rows 0..3 at lg==0, regs 0..3
    float hreg[4];
#pragma unroll
    for (int r = 0; r < 4; ++r) {
      const float ig = sigf(acc[0][r]), fg = sigf(acc[1][r]);
      const float gg = tanhf_(acc[2][r]), og = sigf(acc[3][r]);
      c[r] = fg * c[r] + ig * gg;
      hreg[r] = og * tanhf_(c[r]);
    }

    if (lg == 0) {
      _Float16* wr = &hbuf[t & 1][0][0];
#pragma unroll
      for (int r = 0; r < 4; ++r) wr[r * 144 + col] = (_Float16)hreg[r];
    }

    a1c0 = a1n0; a1c1 = a1n1; a1c2 = a1n2; a1c3 = a1n3;
    BARRIER();
  }

  // final y(511) from h2(511) in hbuf[1]
  if (wave == 0) {
    const _Float16* rd = &hbuf[1][ar][lg * 8];
    const half8 b0 = *(const half8*)(rd + 0);
    const half8 b1 = *(const half8*)(rd + 32);
    const half8 b2 = *(const half8*)(rd + 64);
    const half8 b3 = *(const half8*)(rd + 96);
    f32x4 ya = {ybias, ybias, ybias, ybias};
    ya = MFMA16(b0, wl_f[0], ya);
    ya = MFMA16(b1, wl_f[1], ya);
    ya = MFMA16(b2, wl_f[2], ya);
    ya = MFMA16(b3, wl_f[3], ya);
    if (lg == 0 && lc < 7) {
#pragma unroll
      for (int j = 0; j < 4; ++j)
        out[(size_t)(bid * 4 + j) * 3584 + (size_t)511 * 7 + lc] = ya[j];
    }
  }
}

extern "C" void kernel_launch(void* const* d_in, const int* in_sizes, int n_in,
                              void* d_out, int out_size, void* d_ws, size_t ws_size,
                              hipStream_t stream) {
  (void)in_sizes; (void)n_in; (void)out_size; (void)ws_size;
  const float* x     = (const float*)d_in[0];
  const float* W_ih1 = (const float*)d_in[1];
  const float* W_hh1 = (const float*)d_in[2];
  const float* b_ih1 = (const float*)d_in[3];
  const float* b_hh1 = (const float*)d_in[4];
  const float* W_ih2 = (const float*)d_in[5];
  const float* W_hh2 = (const float*)d_in[6];
  const float* b_ih2 = (const float*)d_in[7];
  const float* b_hh2 = (const float*)d_in[8];
  const float* W_lin = (const float*)d_in[9];
  const float* b_lin = (const float*)d_in[10];
  float* out = (float*)d_out;
  _Float16* h1g = (_Float16*)d_ws;   // [512][1024][128] fp16 = 134,217,728 bytes

  lstm_layer1_kernel<<<512, 512, 0, stream>>>(x, W_ih1, W_hh1, b_ih1, b_hh1, h1g);
  lstm_layer2_kernel<<<256, 512, 0, stream>>>(h1g, W_ih2, W_hh2, b_ih2, b_hh2,
                                              W_lin, b_lin, out);
}

// Round 4
// 946.212 us; speedup vs baseline: 1.4762x; 1.1682x over previous
//
#include <hip/hip_runtime.h>

// LSTMPredictor: B=1024, T=512, IN=19, H=128, OUT=7 (fp32 in/out)
// R=4 rows/block, 256 blocks x 512 threads, 1 block/CU.
// Key invariant: A-frag rows 4..15 duplicate rows 0..3 (all A reads use lc&3),
// so D[4*lg+r] == D[r] and acc_g[r] at EVERY lane holds D_g[r][col=lc].
// Lane (lg,lc) therefore selects its own register acc_g[lg] (3 cndmasks) --
// zero cross-lane ops, zero-redundancy activations, 1 c-reg/lane.
// x staged to LDS fp16 once (L1); h double-buffer 2x1KB; weights in VGPRs.

typedef _Float16 half8 __attribute__((ext_vector_type(8)));
typedef float f32x4 __attribute__((ext_vector_type(4)));

#define MFMA16(a, b, c) __builtin_amdgcn_mfma_f32_16x16x32_f16((a), (b), (c), 0, 0, 0)
#define BARRIER() asm volatile("s_waitcnt lgkmcnt(0)\ns_barrier" ::: "memory")

__device__ __forceinline__ float sigf(float x) {
  return __builtin_amdgcn_rcpf(1.f + __expf(-x));   // NaN-free at +/-inf
}
__device__ __forceinline__ float tanhf_(float x) {
  return 1.f - 2.f * __builtin_amdgcn_rcpf(1.f + __expf(2.f * x));  // NaN-free
}

// acc_g[r] == D_g[r][lc] at every lane (duplication invariant) -> pick reg lg.
__device__ __forceinline__ float sel4(const f32x4 a, const int lg) {
  const float v01 = (lg & 1) ? a[1] : a[0];
  const float v23 = (lg & 1) ? a[3] : a[2];
  return (lg & 2) ? v23 : v01;
}

// ---------------- Layer 1 ----------------
__global__ __launch_bounds__(512) void lstm_layer1_kernel(
    const float* __restrict__ x,        // [1024,512,19]
    const float* __restrict__ Wih,      // [512,19]
    const float* __restrict__ Whh,      // [512,128]
    const float* __restrict__ bih, const float* __restrict__ bhh,
    _Float16* __restrict__ h1g)         // [512][1024][128] fp16 (T-major)
{
  __shared__ _Float16 xls[512][12][8];  // 98,304 B: fp16 x A-frags (k padded to 24)
  __shared__ _Float16 hbuf[2][64][8];   // 2 KiB: [buf][(c3*4+row)][8]
  const int tid = threadIdx.x, bid = blockIdx.x;
  const int wv = tid >> 6, lane = tid & 63;
  const int lg = lane >> 4, lc = lane & 15;
  const int col = wv * 16 + lc;                               // hidden unit
  const int off0 = lg * 32 + (lc & 3) * 8;                    // A-frag read offset (halfs)
  const int woff = ((wv * 2 + (lc >> 3)) * 4 + lg) * 8 + (lc & 7);  // h write offset

  // Weight B-frags: col n = g*128+col, k = lg*8+j
  half8 wih_f[4], whh_f[4][4];
  float bias[4];
#pragma unroll
  for (int g = 0; g < 4; ++g) {
    const int n = g * 128 + col;
    bias[g] = bih[n] + bhh[n];
    half8 f;
#pragma unroll
    for (int j = 0; j < 8; ++j) {
      const int k = lg * 8 + j;
      f[j] = (_Float16)((k < 19) ? Wih[n * 19 + k] : 0.f);
    }
    wih_f[g] = f;
#pragma unroll
    for (int kk = 0; kk < 4; ++kk) {
      const float* p = Whh + n * 128 + kk * 32 + lg * 8;
      half8 f2;
#pragma unroll
      for (int j = 0; j < 8; ++j) f2[j] = (_Float16)p[j];
      whh_f[g][kk] = f2;
    }
  }

  // Stage x rows [4bid..4bid+3] as fp16 A-frags; chunks cc=0..2 (k<24), k>=19 zero.
  for (int i2 = tid; i2 < 512 * 96; i2 += 512) {
    const int t = i2 / 96, r = i2 - t * 96;
    const int cc = r >> 5, rr = (r >> 3) & 3, j = r & 7;
    const int k = cc * 8 + j;
    float v = 0.f;
    if (k < 19) v = x[((size_t)(bid * 4 + rr) * 512 + t) * 19 + k];
    xls[t][cc * 4 + rr][j] = (_Float16)v;
  }
  for (int i = tid; i < 1024; i += 512) ((_Float16*)hbuf)[i] = (_Float16)0.f;
  __syncthreads();

  float c = 0.f;
  _Float16* h1p = h1g + (size_t)(bid * 4 + lg) * 128 + col;  // [t][row][col], t-stride 131072
  const _Float16* xb = &xls[0][0][0] + off0;
  _Float16* hb0p = &hbuf[0][0][0];
  const f32x4 fz = {0.f, 0.f, 0.f, 0.f};
  const bool xv = (lg < 3);

#define L1_STEP(T, RD, WR)                                                    \
  {                                                                           \
    const _Float16* rd = (RD) + off0;                                         \
    const half8 hb0 = *(const half8*)(rd);                                    \
    const half8 hb1 = *(const half8*)(rd + 128);                              \
    const half8 hb2 = *(const half8*)(rd + 256);                              \
    const half8 hb3 = *(const half8*)(rd + 384);                              \
    half8 ax = {};                                                            \
    if (xv) ax = *(const half8*)(xb + (T) * 96);                              \
    f32x4 a0 = MFMA16(ax, wih_f[0], fz);                                      \
    f32x4 a1 = MFMA16(ax, wih_f[1], fz);                                      \
    f32x4 a2 = MFMA16(ax, wih_f[2], fz);                                      \
    f32x4 a3 = MFMA16(ax, wih_f[3], fz);                                      \
    a0 = MFMA16(hb0, whh_f[0][0], a0); a1 = MFMA16(hb0, whh_f[1][0], a1);     \
    a2 = MFMA16(hb0, whh_f[2][0], a2); a3 = MFMA16(hb0, whh_f[3][0], a3);     \
    a0 = MFMA16(hb1, whh_f[0][1], a0); a1 = MFMA16(hb1, whh_f[1][1], a1);     \
    a2 = MFMA16(hb1, whh_f[2][1], a2); a3 = MFMA16(hb1, whh_f[3][1], a3);     \
    a0 = MFMA16(hb2, whh_f[0][2], a0); a1 = MFMA16(hb2, whh_f[1][2], a1);     \
    a2 = MFMA16(hb2, whh_f[2][2], a2); a3 = MFMA16(hb2, whh_f[3][2], a3);     \
    a0 = MFMA16(hb3, whh_f[0][3], a0); a1 = MFMA16(hb3, whh_f[1][3], a1);     \
    a2 = MFMA16(hb3, whh_f[2][3], a2); a3 = MFMA16(hb3, whh_f[3][3], a3);     \
    const float gi = sel4(a0, lg) + bias[0];                                  \
    const float gf = sel4(a1, lg) + bias[1];                                  \
    const float gg = sel4(a2, lg) + bias[2];                                  \
    const float go = sel4(a3, lg) + bias[3];                                  \
    const float I = sigf(gi), F = sigf(gf), G = tanhf_(gg), O = sigf(go);     \
    c = F * c + I * G;                                                        \
    const float h = O * tanhf_(c);                                            \
    const _Float16 h16 = (_Float16)h;                                         \
    (WR)[woff] = h16;                                                         \
    h1p[(size_t)(T) * 131072] = h16;                                          \
    BARRIER();                                                                \
  }

#pragma unroll 1
  for (int t = 0; t < 512; t += 2) {
    L1_STEP(t, hb0p + 512, hb0p);      // even t: read buf1 (h(t-1)), write buf0
    L1_STEP(t + 1, hb0p, hb0p + 512);  // odd t
  }
#undef L1_STEP
}

// ---------------- Layer 2 + Linear ----------------
__global__ __launch_bounds__(512) void lstm_layer2_kernel(
    const _Float16* __restrict__ h1g,   // [512][1024][128]
    const float* __restrict__ Wih,      // [512,128]
    const float* __restrict__ Whh,      // [512,128]
    const float* __restrict__ bih, const float* __restrict__ bhh,
    const float* __restrict__ Wlin,     // [7,128]
    const float* __restrict__ blin,     // [7]
    float* __restrict__ out)            // [1024, 3584]
{
  __shared__ _Float16 hbuf[2][64][8];
  const int tid = threadIdx.x, bid = blockIdx.x;
  const int wv = tid >> 6, lane = tid & 63;
  const int lg = lane >> 4, lc = lane & 15;
  const int col = wv * 16 + lc;
  const int off0 = lg * 32 + (lc & 3) * 8;
  const int woff = ((wv * 2 + (lc >> 3)) * 4 + lg) * 8 + (lc & 7);

  half8 wi_f[4][4], wh_f[4][4];
  float bias[4];
#pragma unroll
  for (int g = 0; g < 4; ++g) {
    const int n = g * 128 + col;
    bias[g] = bih[n] + bhh[n];
#pragma unroll
    for (int kk = 0; kk < 4; ++kk) {
      const float* pi = Wih + n * 128 + kk * 32 + lg * 8;
      const float* ph = Whh + n * 128 + kk * 32 + lg * 8;
      half8 fi, fh;
#pragma unroll
      for (int j = 0; j < 8; ++j) { fi[j] = (_Float16)pi[j]; fh[j] = (_Float16)ph[j]; }
      wi_f[g][kk] = fi;
      wh_f[g][kk] = fh;
    }
  }
  half8 wl_f[4];
  const bool yv = (lc < 7);
  const float ybias = yv ? blin[lc] : 0.f;
#pragma unroll
  for (int kk = 0; kk < 4; ++kk) {
    half8 f;
#pragma unroll
    for (int j = 0; j < 8; ++j)
      f[j] = yv ? (_Float16)Wlin[lc * 128 + kk * 32 + lg * 8 + j] : (_Float16)0.f;
    wl_f[kk] = f;
  }

  for (int i = tid; i < 1024; i += 512) ((_Float16*)hbuf)[i] = (_Float16)0.f;
  __syncthreads();

  float c = 0.f;
  const _Float16* h1p = h1g + (size_t)(bid * 4 + (lc & 3)) * 128 + lg * 8;
  _Float16* hb0p = &hbuf[0][0][0];
  const f32x4 fz = {0.f, 0.f, 0.f, 0.f};

  half8 iA0 = *(const half8*)(h1p);
  half8 iA1 = *(const half8*)(h1p + 32);
  half8 iA2 = *(const half8*)(h1p + 64);
  half8 iA3 = *(const half8*)(h1p + 96);
  half8 iB0 = {}, iB1 = {}, iB2 = {}, iB3 = {};

#define L2_STEP(T, RD, WR, IC0, IC1, IC2, IC3, IN0, IN1, IN2, IN3)            \
  {                                                                           \
    const _Float16* rd = (RD) + off0;                                         \
    const half8 hb0 = *(const half8*)(rd);                                    \
    const half8 hb1 = *(const half8*)(rd + 128);                              \
    const half8 hb2 = *(const half8*)(rd + 256);                              \
    const half8 hb3 = *(const half8*)(rd + 384);                              \
    const size_t tn = (size_t)((T) + 1 < 512 ? (T) + 1 : 511) * 131072;       \
    IN0 = *(const half8*)(h1p + tn);                                          \
    IN1 = *(const half8*)(h1p + tn + 32);                                     \
    IN2 = *(const half8*)(h1p + tn + 64);                                     \
    IN3 = *(const half8*)(h1p + tn + 96);                                     \
    f32x4 a0 = MFMA16(IC0, wi_f[0][0], fz);                                   \
    f32x4 a1 = MFMA16(IC0, wi_f[1][0], fz);                                   \
    f32x4 a2 = MFMA16(IC0, wi_f[2][0], fz);                                   \
    f32x4 a3 = MFMA16(IC0, wi_f[3][0], fz);                                   \
    a0 = MFMA16(IC1, wi_f[0][1], a0); a1 = MFMA16(IC1, wi_f[1][1], a1);       \
    a2 = MFMA16(IC1, wi_f[2][1], a2); a3 = MFMA16(IC1, wi_f[3][1], a3);       \
    a0 = MFMA16(IC2, wi_f[0][2], a0); a1 = MFMA16(IC2, wi_f[1][2], a1);       \
    a2 = MFMA16(IC2, wi_f[2][2], a2); a3 = MFMA16(IC2, wi_f[3][2], a3);       \
    a0 = MFMA16(IC3, wi_f[0][3], a0); a1 = MFMA16(IC3, wi_f[1][3], a1);       \
    a2 = MFMA16(IC3, wi_f[2][3], a2); a3 = MFMA16(IC3, wi_f[3][3], a3);       \
    a0 = MFMA16(hb0, wh_f[0][0], a0); a1 = MFMA16(hb0, wh_f[1][0], a1);       \
    a2 = MFMA16(hb0, wh_f[2][0], a2); a3 = MFMA16(hb0, wh_f[3][0], a3);       \
    a0 = MFMA16(hb1, wh_f[0][1], a0); a1 = MFMA16(hb1, wh_f[1][1], a1);       \
    a2 = MFMA16(hb1, wh_f[2][1], a2); a3 = MFMA16(hb1, wh_f[3][1], a3);       \
    a0 = MFMA16(hb2, wh_f[0][2], a0); a1 = MFMA16(hb2, wh_f[1][2], a1);       \
    a2 = MFMA16(hb2, wh_f[2][2], a2); a3 = MFMA16(hb2, wh_f[3][2], a3);       \
    a0 = MFMA16(hb3, wh_f[0][3], a0); a1 = MFMA16(hb3, wh_f[1][3], a1);       \
    a2 = MFMA16(hb3, wh_f[2][3], a2); a3 = MFMA16(hb3, wh_f[3][3], a3);       \
    if (wv == 0 && (T) > 0) {                                                 \
      f32x4 ya = {ybias, ybias, ybias, ybias};                                \
      ya = MFMA16(hb0, wl_f[0], ya);                                          \
      ya = MFMA16(hb1, wl_f[1], ya);                                          \
      ya = MFMA16(hb2, wl_f[2], ya);                                          \
      ya = MFMA16(hb3, wl_f[3], ya);                                          \
      if (lg == 0 && yv) {                                                    \
        _Pragma("unroll")                                                     \
        for (int j = 0; j < 4; ++j)                                           \
          out[(size_t)(bid * 4 + j) * 3584 + (size_t)((T)-1) * 7 + lc] = ya[j]; \
      }                                                                       \
    }                                                                         \
    const float gi = sel4(a0, lg) + bias[0];                                  \
    const float gf = sel4(a1, lg) + bias[1];                                  \
    const float gg = sel4(a2, lg) + bias[2];                                  \
    const float go = sel4(a3, lg) + bias[3];                                  \
    const float I = sigf(gi), F = sigf(gf), G = tanhf_(gg), O = sigf(go);     \
    c = F * c + I * G;                                                        \
    const float h = O * tanhf_(c);                                            \
    (WR)[woff] = (_Float16)h;                                                 \
    BARRIER();                                                                \
  }

#pragma unroll 1
  for (int t = 0; t < 512; t += 2) {
    L2_STEP(t, hb0p + 512, hb0p, iA0, iA1, iA2, iA3, iB0, iB1, iB2, iB3);
    L2_STEP(t + 1, hb0p, hb0p + 512, iB0, iB1, iB2, iB3, iA0, iA1, iA2, iA3);
  }
#undef L2_STEP

  // y(511) from h2(511) sitting in buf1 (written at t=511; barrier passed)
  if (wv == 0) {
    const _Float16* rd = hb0p + 512 + off0;
    const half8 hb0 = *(const half8*)(rd);
    const half8 hb1 = *(const half8*)(rd + 128);
    const half8 hb2 = *(const half8*)(rd + 256);
    const half8 hb3 = *(const half8*)(rd + 384);
    f32x4 ya = {ybias, ybias, ybias, ybias};
    ya = MFMA16(hb0, wl_f[0], ya);
    ya = MFMA16(hb1, wl_f[1], ya);
    ya = MFMA16(hb2, wl_f[2], ya);
    ya = MFMA16(hb3, wl_f[3], ya);
    if (lg == 0 && yv) {
#pragma unroll
      for (int j = 0; j < 4; ++j)
        out[(size_t)(bid * 4 + j) * 3584 + (size_t)511 * 7 + lc] = ya[j];
    }
  }
}

extern "C" void kernel_launch(void* const* d_in, const int* in_sizes, int n_in,
                              void* d_out, int out_size, void* d_ws, size_t ws_size,
                              hipStream_t stream) {
  (void)in_sizes; (void)n_in; (void)out_size; (void)ws_size;
  const float* x     = (const float*)d_in[0];
  const float* W_ih1 = (const float*)d_in[1];
  const float* W_hh1 = (const float*)d_in[2];
  const float* b_ih1 = (const float*)d_in[3];
  const float* b_hh1 = (const float*)d_in[4];
  const float* W_ih2 = (const float*)d_in[5];
  const float* W_hh2 = (const float*)d_in[6];
  const float* b_ih2 = (const float*)d_in[7];
  const float* b_hh2 = (const float*)d_in[8];
  const float* W_lin = (const float*)d_in[9];
  const float* b_lin = (const float*)d_in[10];
  float* out = (float*)d_out;
  _Float16* h1g = (_Float16*)d_ws;   // [512][1024][128] fp16 = 134,217,728 bytes

  lstm_layer1_kernel<<<256, 512, 0, stream>>>(x, W_ih1, W_hh1, b_ih1, b_hh1, h1g);
  lstm_layer2_kernel<<<256, 512, 0, stream>>>(h1g, W_ih2, W_hh2, b_ih2, b_hh2,
                                              W_lin, b_lin, out);
}